// Round 1
// baseline (736.367 us; speedup 1.0000x reference)
//
#include <hip/hip_runtime.h>
#include <math.h>

// Problem constants (from reference)
#define NQ    1224            // NUM_OF_QUES
#define NS    50              // MAX_STEPS
#define NB    1024            // BATCH
#define ROW   (2 * NQ)        // 2448 floats per batch row
#define ROW4  (ROW / 4)       // 612 float4 per row
#define PAIRS (NB * (NS - 1)) // 50176 (b, step) pairs
#define NCHUNK 10             // ceil(612/64) chunks of 64 float4 per row

__global__ void zero_out_kernel(float* out) {
    out[0] = 0.0f;
}

// One wave (64 lanes) per (b, step) pair, grid-stride over pairs.
//
// THEORY-DRIVEN CHANGE vs previous version: the per-chunk __any() early exit
// made every 1 KB chunk a DEPENDENT round trip (load -> vmcnt(0) -> ballot ->
// branch -> next load), capping each wave at 1 KB in flight and ~32 serial HBM
// round trips. That is latency-bound (~0.5 TB/s effective), 10x under the BW
// roofline. This version reads the FULL row with a fixed-trip-count unrolled
// loop: all 10 global_load_dwordx4 are independent and issued back-to-back
// (memcpy-shaped stream, the pattern that achieves 6.3 TB/s). We pay ~1.8x the
// bytes of the early-exit scheme but become purely BW-bound: ~495 MB total ->
// ~85-100 us predicted.
//
// Exactly one float in each 2448-float row is nonzero (== 1.0): position q if
// the answer was correct, q + NQ if incorrect. The lane holding it gathers
// pred[b, si, q] and accumulates the BCE term; wave shuffle-reduce -> LDS ->
// one atomicAdd per block.
__global__ __launch_bounds__(256) void dkt_loss_kernel(
        const float* __restrict__ pred,    // [NB, NS, NQ]
        const float* __restrict__ batch,   // [NB, NS, 2*NQ]
        float* __restrict__ out) {
    __shared__ float wpart[4];

    const int lane = threadIdx.x & 63;
    const int wid  = threadIdx.x >> 6;
    const int gw   = blockIdx.x * 4 + wid;   // global wave id
    const int nw   = gridDim.x * 4;          // total waves (7168)

    float wsum = 0.0f;

    // 7168 waves x exactly 7 pairs = 50176: zero tail imbalance.
    for (int pair = gw; pair < PAIRS; pair += nw) {
        const int b  = pair / 49;            // student (compiler -> magic mul)
        const int si = pair - b * 49;        // pred step, 0..48
        const int s  = si + 1;               // batch step, 1..49

        const float4* row =
            (const float4*)batch + (size_t)(b * NS + s) * ROW4;

        int found = -1;
        // Fixed trip count, fully unrolled, NO early exit: the compiler emits
        // 10 independent global_load_dwordx4 (40 data VGPRs in flight) and
        // interleaves the compare chains under descending vmcnt waits.
        #pragma unroll
        for (int k = 0; k < NCHUNK; ++k) {
            const int i4 = lane + (k << 6);
            float4 v = make_float4(0.f, 0.f, 0.f, 0.f);
            if (i4 < ROW4) v = row[i4];      // only k==9 is actually masked
            if (v.x != 0.0f) found = i4 * 4 + 0;
            if (v.y != 0.0f) found = i4 * 4 + 1;
            if (v.z != 0.0f) found = i4 * 4 + 2;
            if (v.w != 0.0f) found = i4 * 4 + 3;
        }

        // Exactly one lane (one component) holds the one-hot index.
        if (found >= 0) {
            const int  a = (found < NQ) ? 1 : 0;
            const int  q = a ? found : (found - NQ);
            const float p = pred[((size_t)b * NS + si) * NQ + q];
            wsum += a ? -logf(p) : -logf(1.0f - p);
        }
    }

    // Wave reduction (64 lanes)
    #pragma unroll
    for (int off = 32; off > 0; off >>= 1)
        wsum += __shfl_down(wsum, off, 64);

    if (lane == 0) wpart[wid] = wsum;
    __syncthreads();
    if (threadIdx.x == 0)
        atomicAdd(out, wpart[0] + wpart[1] + wpart[2] + wpart[3]);
}

extern "C" void kernel_launch(void* const* d_in, const int* in_sizes, int n_in,
                              void* d_out, int out_size, void* d_ws, size_t ws_size,
                              hipStream_t stream) {
    const float* pred  = (const float*)d_in[0];   // [1024, 50, 1224] f32
    const float* batch = (const float*)d_in[1];   // [1024, 50, 2448] f32
    float* out = (float*)d_out;                   // [1] f32

    // d_out is poisoned to 0xAA before every timed launch — zero it first.
    zero_out_kernel<<<1, 1, 0, stream>>>(out);

    // 1792 blocks x 256 threads = 7168 waves (28/CU), 7 pairs per wave exactly.
    dkt_loss_kernel<<<1792, 256, 0, stream>>>(pred, batch, out);
}

// Round 2
// 696.864 us; speedup vs baseline: 1.0567x; 1.0567x over previous
//
#include <hip/hip_runtime.h>
#include <math.h>

// Problem constants (from reference)
#define NQ    1224            // NUM_OF_QUES
#define NS    50              // MAX_STEPS
#define NB    1024            // BATCH
#define ROW   (2 * NQ)        // 2448 floats per batch row
#define ROW4  (ROW / 4)       // 612 float4 per row
#define PAIRS (NB * (NS - 1)) // 50176 (b, step) pairs
#define NCHUNK 10             // ceil(612/64) chunks of 64 float4 per row

__global__ void zero_out_kernel(float* out) {
    out[0] = 0.0f;
}

// MEASURED MODEL (round 1 counters + arithmetic):
//   dur_us = ~658 us constant harness overhead (2x 309us fillBufferAligned
//            poison dispatches at 6.5 TB/s + launch/tail slop)
//          + kernel time, which is purely HBM-BW-bound at ~6.3-6.4 TB/s.
//   full-read (491 MB)   -> 78 us kernel -> 736.4 us total (measured)
//   early-exit (~272 MB) -> 42 us kernel -> 700.6 us total (measured)
// The round-0 "dependent round trips kill BW" theory was WRONG: with 32
// waves/CU x 1 KB in flight (32 KB/CU >> ~10 KB/CU needed for 6.3 TB/s),
// the early-exit chain still saturates HBM. Byte count is the only lever,
// and 55% expected traffic is ~the floor (50% + half-chunk granularity).
//
// One wave (64 lanes) per (b, step) pair, grid-stride over pairs. Each wave
// scans its 2448-float batch row in 1 KB chunks (64 lanes x float4, perfectly
// coalesced) and EARLY-EXITS via wave ballot once the single one-hot entry is
// found: expected traffic ~55% of the full row. The finding lane gathers pred
// and accumulates the BCE term. Wave shuffle-reduce -> LDS -> one atomicAdd
// per block.
__global__ __launch_bounds__(256) void dkt_loss_kernel(
        const float* __restrict__ pred,    // [NB, NS, NQ]
        const float* __restrict__ batch,   // [NB, NS, 2*NQ]
        float* __restrict__ out) {
    __shared__ float wpart[4];

    const int lane = threadIdx.x & 63;
    const int wid  = threadIdx.x >> 6;
    const int gw   = blockIdx.x * 4 + wid;   // global wave id
    const int nw   = gridDim.x * 4;          // total waves

    float wsum = 0.0f;

    for (int pair = gw; pair < PAIRS; pair += nw) {
        const int b  = pair / 49;            // student (compiler -> magic mul)
        const int si = pair - b * 49;        // pred step, 0..48
        const int s  = si + 1;               // batch step, 1..49

        const float4* row =
            (const float4*)batch + (size_t)(b * NS + s) * ROW4;

        int found = -1;
        for (int k = 0; k < NCHUNK; ++k) {
            const int i4 = lane + (k << 6);
            float4 v = make_float4(0.f, 0.f, 0.f, 0.f);
            if (i4 < ROW4) v = row[i4];
            if (v.x != 0.0f) found = i4 * 4 + 0;
            if (v.y != 0.0f) found = i4 * 4 + 1;
            if (v.z != 0.0f) found = i4 * 4 + 2;
            if (v.w != 0.0f) found = i4 * 4 + 3;
            // Wave-uniform early exit: skip the rest of the row (dead bytes).
            if (__any(found >= 0)) break;
        }

        // Exactly one lane (one component) holds the one-hot index.
        if (found >= 0) {
            const int  a = (found < NQ) ? 1 : 0;
            const int  q = a ? found : (found - NQ);
            const float p = pred[((size_t)b * NS + si) * NQ + q];
            wsum += a ? -logf(p) : -logf(1.0f - p);
        }
    }

    // Wave reduction (64 lanes)
    #pragma unroll
    for (int off = 32; off > 0; off >>= 1)
        wsum += __shfl_down(wsum, off, 64);

    if (lane == 0) wpart[wid] = wsum;
    __syncthreads();
    if (threadIdx.x == 0)
        atomicAdd(out, wpart[0] + wpart[1] + wpart[2] + wpart[3]);
}

extern "C" void kernel_launch(void* const* d_in, const int* in_sizes, int n_in,
                              void* d_out, int out_size, void* d_ws, size_t ws_size,
                              hipStream_t stream) {
    const float* pred  = (const float*)d_in[0];   // [1024, 50, 1224] f32
    const float* batch = (const float*)d_in[1];   // [1024, 50, 2448] f32
    float* out = (float*)d_out;                   // [1] f32

    // d_out is poisoned to 0xAA before every timed launch — zero it first.
    zero_out_kernel<<<1, 1, 0, stream>>>(out);

    // 2048 blocks x 256 threads = 8192 waves (32/CU): max TLP so the
    // early-exit dependent chain stays HBM-BW-bound (proven-best config).
    dkt_loss_kernel<<<2048, 256, 0, stream>>>(pred, batch, out);
}